// Round 4
// baseline (1045.721 us; speedup 1.0000x reference)
//
#include <hip/hip_runtime.h>
#include <hip/hip_bf16.h>

#define NE 8
#define FF 4096
#define HH 2048
#define TT 2048
#define KTOP 4

typedef unsigned short u16;
typedef __attribute__((ext_vector_type(8))) short bf16x8;
typedef __attribute__((ext_vector_type(4))) float f32x4;

__device__ __forceinline__ u16 f2u(float f) {
  __hip_bfloat16 b = __float2bfloat16(f);
  return *reinterpret_cast<u16*>(&b);
}

__device__ __forceinline__ void gld16(void* lds, const void* g) {
  __builtin_amdgcn_global_load_lds(
      (const __attribute__((address_space(1))) void*)g,
      (__attribute__((address_space(3))) void*)lds, 16, 0, 0);
}

// Per-expert token lists, deterministic (token ascending).
__global__ void k_build(const int* __restrict__ te, int* __restrict__ cnt,
                        int* __restrict__ tok, int* __restrict__ posmap) {
  const int e = blockIdx.x;
  const int tl = threadIdx.x;          // 256 threads, 8 tokens each
  const int base = tl * 8;
  int mem[8];
  int my = 0;
  #pragma unroll
  for (int i = 0; i < 8; ++i) {
    const int t = base + i;
    bool m = false;
    #pragma unroll
    for (int k = 0; k < KTOP; ++k) m |= (te[t * KTOP + k] == e);
    mem[i] = m ? 1 : 0;
    my += mem[i];
  }
  __shared__ int s[256];
  s[tl] = my;
  __syncthreads();
  for (int off = 1; off < 256; off <<= 1) {
    int v = (tl >= off) ? s[tl - off] : 0;
    __syncthreads();
    s[tl] += v;
    __syncthreads();
  }
  int r = s[tl] - my;
  if (tl == 255) cnt[e] = s[255];
  #pragma unroll
  for (int i = 0; i < 8; ++i) {
    if (mem[i]) {
      const int t = base + i;
      tok[e * TT + r] = t;
      posmap[t * NE + e] = r;
      ++r;
    }
  }
}

__global__ void k_cast4(const float4* __restrict__ src, ushort4* __restrict__ dst, int n4) {
  int stride = gridDim.x * blockDim.x;
  for (int i = blockIdx.x * blockDim.x + threadIdx.x; i < n4; i += stride) {
    float4 f = src[i];
    ushort4 o;
    o.x = f2u(f.x); o.y = f2u(f.y); o.z = f2u(f.z); o.w = f2u(f.w);
    dst[i] = o;
  }
}

// w1,v1 -> combined w12[e][8192][HH] bf16, 16-row interleave:
// w12 rows 32j..32j+15 = w1 rows 16j.., rows 32j+16..32j+31 = v1 rows 16j..
__global__ void k_cast12(const float* __restrict__ w1, const float* __restrict__ v1,
                         u16* __restrict__ w12) {
  const long i = (long)blockIdx.x * 256 + threadIdx.x;  // over NE*FF*HH/8
  const int k8 = (int)(i & 255);                        // HH/8 = 256
  const long fe = i >> 8;
  const int f = (int)(fe & (FF - 1));
  const int e = (int)(fe >> 12);
  const size_t so = ((size_t)(e * FF + f)) * HH + (size_t)k8 * 8;
  const int cr = ((f >> 4) << 5) + (f & 15);
  u16* d1 = w12 + ((size_t)e * 2 * FF + cr) * HH + (size_t)k8 * 8;
  u16* d2 = d1 + (size_t)16 * HH;
  float4 a = ((const float4*)(w1 + so))[0];
  float4 b = ((const float4*)(w1 + so))[1];
  ((ushort4*)d1)[0] = (ushort4){f2u(a.x), f2u(a.y), f2u(a.z), f2u(a.w)};
  ((ushort4*)d1)[1] = (ushort4){f2u(b.x), f2u(b.y), f2u(b.z), f2u(b.w)};
  a = ((const float4*)(v1 + so))[0];
  b = ((const float4*)(v1 + so))[1];
  ((ushort4*)d2)[0] = (ushort4){f2u(a.x), f2u(a.y), f2u(a.z), f2u(a.w)};
  ((ushort4*)d2)[1] = (ushort4){f2u(b.x), f2u(b.y), f2u(b.z), f2u(b.w)};
}

// w2[e]: [FF][HH] fp32 -> [HH][FF] bf16 transposed
__global__ void k_tcast(const float* __restrict__ w2, u16* __restrict__ dst) {
  const int e = blockIdx.z;
  const float* src = w2 + (size_t)e * FF * HH;
  u16* d = dst + (size_t)e * HH * FF;
  __shared__ float tile[32][33];
  int h0 = blockIdx.x * 32;
  int f0 = blockIdx.y * 32;
  int tx = threadIdx.x, ty = threadIdx.y;
  #pragma unroll
  for (int i = 0; i < 4; ++i)
    tile[ty + i*8][tx] = src[(size_t)(f0 + ty + i*8) * HH + h0 + tx];
  __syncthreads();
  #pragma unroll
  for (int i = 0; i < 4; ++i)
    d[(size_t)(h0 + ty + i*8) * FF + f0 + tx] = f2u(tile[tx][ty + i*8]);
}

// gather x rows into per-expert panels, zero-pad to 256 multiple.
__global__ void k_gather(const u16* __restrict__ xb, const int* __restrict__ tok,
                         const int* __restrict__ cnt, u16* __restrict__ xg) {
  const int e = blockIdx.y;
  const int r = blockIdx.x;
  const int c = cnt[e];
  const int mcap = (c + 255) & ~255;
  if (r >= mcap) return;
  uint4* dst = (uint4*)(xg + ((size_t)e * TT + r) * HH) + threadIdx.x;
  if (r < c) {
    const uint4* src = (const uint4*)(xb + (size_t)tok[e * TT + r] * HH) + threadIdx.x;
    *dst = *src;
  } else {
    *dst = (uint4){0, 0, 0, 0};
  }
}

// 256x256 pipelined bf16 GEMM, BK=64, 8 waves (2Mx4N), 128KB dbuf LDS,
// counted vmcnt + raw barriers, T2 row-XOR swizzle, quadrant phases + setprio.
// Block order: (e, ntl, mt) with mt innermost -> same-B-panel blocks adjacent
// (8 blocks share one 1MB B panel; 256-block window = one expert => L2/LLC reuse).
// MODE 0: GLU  A=xg[e] (K=2048), B=w12[e] (8192 rows), out hc bf16 silu-fused
// MODE 1: down A=hc[e] (K=4096), B=w2t[e] (2048 rows), out dcomp fp32
template<int MODE>
__global__ __launch_bounds__(512)
void gemm256(const u16* __restrict__ Aall, const u16* __restrict__ Ball,
             const int* __restrict__ cnt, void* __restrict__ Oall) {
  constexpr int KD  = (MODE == 0) ? HH : FF;   // 2048 / 4096
  constexpr int NTK = KD / 64;                 // 32 / 64
  constexpr int NT  = (MODE == 0) ? 32 : 8;    // N tiles
  constexpr int NB  = (MODE == 0) ? 2 * FF : HH;

  const int bid = blockIdx.x;
  const int e   = bid / (8 * NT);
  const int rem = bid % (8 * NT);
  const int ntl = rem / 8;        // B tile (outer)
  const int mt  = rem % 8;        // A tile (inner -> adjacent blocks share B)
  const int c = cnt[e];
  const int mcap = (c + 255) & ~255;
  if (mt * 256 >= mcap) return;

  __shared__ __align__(16) u16 smem[65536];    // 128 KB
  u16* const As0 = smem;
  u16* const As1 = smem + 16384;
  u16* const Bs0 = smem + 32768;
  u16* const Bs1 = smem + 49152;

  const int tid  = threadIdx.x;
  const int lane = tid & 63;
  const int wave = tid >> 6;
  const int wm = wave >> 2;      // 0..1
  const int wn = wave & 3;       // 0..3

  const u16* A = Aall + (size_t)e * TT * KD + (size_t)(mt * 256) * KD;
  const u16* B = Ball + (size_t)e * NB * KD + (size_t)(ntl * 256) * KD;

  // staging: linear LDS dest, pre-swizzled global source col (rule 21)
  const int srow = tid >> 3;                                   // 0..63
  const int scol = (((tid & 7) ^ ((tid >> 3) & 7)) << 3);      // u16 units
  const u16* Asrc0 = A + (size_t)(0 * 64 + srow) * KD + scol;
  const u16* Asrc1 = A + (size_t)(1 * 64 + srow) * KD + scol;
  const u16* Asrc2 = A + (size_t)(2 * 64 + srow) * KD + scol;
  const u16* Asrc3 = A + (size_t)(3 * 64 + srow) * KD + scol;
  const u16* Bsrc0 = B + (size_t)(0 * 64 + srow) * KD + scol;
  const u16* Bsrc1 = B + (size_t)(1 * 64 + srow) * KD + scol;
  const u16* Bsrc2 = B + (size_t)(2 * 64 + srow) * KD + scol;
  const u16* Bsrc3 = B + (size_t)(3 * 64 + srow) * KD + scol;

  auto stage = [&](u16* ad, u16* bd, int kt) {
    const int ko = kt * 64;
    u16* a = ad + tid * 8;
    u16* b = bd + tid * 8;
    gld16(a,            Asrc0 + ko);
    gld16(a + 4096,     Asrc1 + ko);
    gld16(a + 8192,     Asrc2 + ko);
    gld16(a + 12288,    Asrc3 + ko);
    gld16(b,            Bsrc0 + ko);
    gld16(b + 4096,     Bsrc1 + ko);
    gld16(b + 8192,     Bsrc2 + ko);
    gld16(b + 12288,    Bsrc3 + ko);
  };

  f32x4 acc[8][4];
  #pragma unroll
  for (int m = 0; m < 8; ++m)
    #pragma unroll
    for (int n = 0; n < 4; ++n)
      acc[m][n] = (f32x4){0.f, 0.f, 0.f, 0.f};

  const int lr = lane & 15;
  // swizzled col part per ks (u16 units): (ks*32 + (lane>>4)*8) ^ ((lane&7)*8)
  const int cs0 = ((0 << 5) + (((lane >> 4) & 3) << 3)) ^ ((lane & 7) << 3);
  const int cs1 = ((1 << 5) + (((lane >> 4) & 3) << 3)) ^ ((lane & 7) << 3);

  // 4 quadrant phases per K-tile: 12 ds_read -> lgkm(0) -> 16 MFMA (setprio).
  auto compute = [&](const u16* ab, const u16* bb) {
    #pragma unroll
    for (int q = 0; q < 4; ++q) {
      const int mq = q >> 1, nq = q & 1;
      bf16x8 af[2][4], bfr[2][2];
      #pragma unroll
      for (int ks = 0; ks < 2; ++ks) {
        const int cpp = ks ? cs1 : cs0;
        #pragma unroll
        for (int n = 0; n < 2; ++n)
          bfr[ks][n] = *(const bf16x8*)(bb + ((wn*64 + nq*32 + n*16 + lr) << 6) + cpp);
        #pragma unroll
        for (int m = 0; m < 4; ++m)
          af[ks][m] = *(const bf16x8*)(ab + ((wm*128 + mq*64 + m*16 + lr) << 6) + cpp);
      }
      asm volatile("s_waitcnt lgkmcnt(0)" ::: "memory");
      __builtin_amdgcn_sched_barrier(0);
      __builtin_amdgcn_s_setprio(1);
      #pragma unroll
      for (int ks = 0; ks < 2; ++ks)
        #pragma unroll
        for (int m = 0; m < 4; ++m)
          #pragma unroll
          for (int n = 0; n < 2; ++n)
            acc[mq*4+m][nq*2+n] = __builtin_amdgcn_mfma_f32_16x16x32_bf16(
                af[ks][m], bfr[ks][n], acc[mq*4+m][nq*2+n], 0, 0, 0);
      __builtin_amdgcn_s_setprio(0);
      __builtin_amdgcn_sched_barrier(0);
    }
  };

  // pipeline: 2 K-tiles in flight, vmcnt(8) = keep next tile's 8 loads pending
  stage(As0, Bs0, 0);
  stage(As1, Bs1, 1);
  for (int t = 0; t < NTK; ++t) {
    if (t == NTK - 1) { asm volatile("s_waitcnt vmcnt(0)" ::: "memory"); }
    else              { asm volatile("s_waitcnt vmcnt(8)" ::: "memory"); }
    __builtin_amdgcn_s_barrier();
    __builtin_amdgcn_sched_barrier(0);
    const int b = t & 1;
    compute(b ? As1 : As0, b ? Bs1 : Bs0);
    __builtin_amdgcn_sched_barrier(0);
    __builtin_amdgcn_s_barrier();
    __builtin_amdgcn_sched_barrier(0);
    if (t + 2 < NTK) stage(b ? As1 : As0, b ? Bs1 : Bs0, t + 2);
  }

  // C/D: col = lane&15, row = (lane>>4)*4 + j  (verified)
  const int rb = mt * 256 + wm * 128 + ((lane >> 4) << 2);
  if (MODE == 0) {
    u16* H = (u16*)Oall + (size_t)e * TT * FF;
    const int fb = ntl * 128 + wn * 32 + lr;
    #pragma unroll
    for (int m = 0; m < 8; ++m)
      #pragma unroll
      for (int np = 0; np < 2; ++np)
        #pragma unroll
        for (int j = 0; j < 4; ++j) {
          float g = acc[m][2*np][j];
          float u = acc[m][2*np + 1][j];
          float hh = (g / (1.f + __expf(-g))) * u;
          H[(size_t)(rb + m*16 + j) * FF + fb + np*16] = f2u(hh);
        }
  } else {
    float* D = (float*)Oall + (size_t)e * TT * HH;
    const int cb = ntl * 256 + wn * 64 + lr;
    #pragma unroll
    for (int m = 0; m < 8; ++m)
      #pragma unroll
      for (int n = 0; n < 4; ++n)
        #pragma unroll
        for (int j = 0; j < 4; ++j)
          D[(size_t)(rb + m*16 + j) * HH + cb + n*16] = acc[m][n][j];
  }
}

__global__ void k_combine(const float* __restrict__ tw, const int* __restrict__ te,
                          const int* __restrict__ posmap, const float* __restrict__ dcomp,
                          float* __restrict__ out) {
  const int t = blockIdx.x;
  const int c0 = threadIdx.x * 8;
  float a[8] = {0.f, 0.f, 0.f, 0.f, 0.f, 0.f, 0.f, 0.f};
  #pragma unroll
  for (int k = 0; k < KTOP; ++k) {
    const int e = te[t * KTOP + k];
    const float w = tw[t * KTOP + k];
    const int r = posmap[t * NE + e];
    const float* row = dcomp + ((size_t)e * TT + r) * HH + c0;
    const float4 p = ((const float4*)row)[0];
    const float4 q = ((const float4*)row)[1];
    a[0] += w * p.x; a[1] += w * p.y; a[2] += w * p.z; a[3] += w * p.w;
    a[4] += w * q.x; a[5] += w * q.y; a[6] += w * q.z; a[7] += w * q.w;
  }
  float* o = out + (size_t)t * HH + c0;
  ((float4*)o)[0] = (float4){a[0], a[1], a[2], a[3]};
  ((float4*)o)[1] = (float4){a[4], a[5], a[6], a[7]};
}

extern "C" void kernel_launch(void* const* d_in, const int* in_sizes, int n_in,
                              void* d_out, int out_size, void* d_ws, size_t ws_size,
                              hipStream_t stream) {
  const float* x  = (const float*)d_in[0];
  const float* tw = (const float*)d_in[2];
  const int*   te = (const int*)d_in[3];
  const float* w1 = (const float*)d_in[4];
  const float* v1 = (const float*)d_in[5];
  const float* w2 = (const float*)d_in[6];
  float* out = (float*)d_out;

  char* p = (char*)d_ws;
  int*   cnt    = (int*)p;   p += 256;
  int*   tok    = (int*)p;   p += (size_t)NE * TT * 4;
  int*   posmap = (int*)p;   p += (size_t)TT * NE * 4;
  u16*   xb     = (u16*)p;   p += (size_t)TT * HH * 2;            // 8 MB
  u16*   xg     = (u16*)p;   p += (size_t)NE * TT * HH * 2;       // 64 MB
  u16*   w12b   = (u16*)p;   p += (size_t)NE * 2 * FF * HH * 2;   // 268 MB
  u16*   w2tb   = (u16*)p;   p += (size_t)NE * HH * FF * 2;       // 134 MB
  u16*   hc     = (u16*)p;   p += (size_t)NE * TT * FF * 2;       // 134 MB
  float* dcomp  = (float*)p; p += (size_t)NE * TT * HH * 4;       // 134 MB

  k_build<<<NE, 256, 0, stream>>>(te, cnt, tok, posmap);
  k_cast4<<<1024, 256, 0, stream>>>((const float4*)x, (ushort4*)xb, TT * HH / 4);
  k_cast12<<<NE * FF * (HH / 8) / 256, 256, 0, stream>>>(w1, v1, w12b);
  k_tcast<<<dim3(HH / 32, FF / 32, NE), dim3(32, 8), 0, stream>>>(w2, w2tb);
  k_gather<<<dim3(TT, NE), 256, 0, stream>>>(xb, tok, cnt, xg);

  // GLU: 8 e x 32 ntl x 8 mt = 2048 blocks
  gemm256<0><<<2048, 512, 0, stream>>>(xg, w12b, cnt, hc);
  // down: 8 e x 8 ntl x 8 mt = 512 blocks
  gemm256<1><<<512, 512, 0, stream>>>(hc, w2tb, cnt, dcomp);
  k_combine<<<TT, 256, 0, stream>>>(tw, te, posmap, dcomp, out);
}

// Round 5
// 991.054 us; speedup vs baseline: 1.0552x; 1.0552x over previous
//
#include <hip/hip_runtime.h>
#include <hip/hip_bf16.h>

#define NE 8
#define FF 4096
#define HH 2048
#define TT 2048
#define KTOP 4

typedef unsigned short u16;
typedef __attribute__((ext_vector_type(8))) short bf16x8;
typedef __attribute__((ext_vector_type(4))) float f32x4;

__device__ __forceinline__ u16 f2u(float f) {
  __hip_bfloat16 b = __float2bfloat16(f);
  return *reinterpret_cast<u16*>(&b);
}

__device__ __forceinline__ void gld16(void* lds, const void* g) {
  __builtin_amdgcn_global_load_lds(
      (const __attribute__((address_space(1))) void*)g,
      (__attribute__((address_space(3))) void*)lds, 16, 0, 0);
}

// Per-expert token lists, deterministic (token ascending).
__global__ void k_build(const int* __restrict__ te, int* __restrict__ cnt,
                        int* __restrict__ tok, int* __restrict__ posmap) {
  const int e = blockIdx.x;
  const int tl = threadIdx.x;          // 256 threads, 8 tokens each
  const int base = tl * 8;
  int mem[8];
  int my = 0;
  #pragma unroll
  for (int i = 0; i < 8; ++i) {
    const int t = base + i;
    bool m = false;
    #pragma unroll
    for (int k = 0; k < KTOP; ++k) m |= (te[t * KTOP + k] == e);
    mem[i] = m ? 1 : 0;
    my += mem[i];
  }
  __shared__ int s[256];
  s[tl] = my;
  __syncthreads();
  for (int off = 1; off < 256; off <<= 1) {
    int v = (tl >= off) ? s[tl - off] : 0;
    __syncthreads();
    s[tl] += v;
    __syncthreads();
  }
  int r = s[tl] - my;
  if (tl == 255) cnt[e] = s[255];
  #pragma unroll
  for (int i = 0; i < 8; ++i) {
    if (mem[i]) {
      const int t = base + i;
      tok[e * TT + r] = t;
      posmap[t * NE + e] = r;
      ++r;
    }
  }
}

__global__ void k_cast4(const float4* __restrict__ src, ushort4* __restrict__ dst, int n4) {
  int stride = gridDim.x * blockDim.x;
  for (int i = blockIdx.x * blockDim.x + threadIdx.x; i < n4; i += stride) {
    float4 f = src[i];
    ushort4 o;
    o.x = f2u(f.x); o.y = f2u(f.y); o.z = f2u(f.z); o.w = f2u(f.w);
    dst[i] = o;
  }
}

// w1,v1 -> combined w12[e][8192][HH] bf16, 16-row interleave:
// w12 rows 32j..32j+15 = w1 rows 16j.., rows 32j+16..32j+31 = v1 rows 16j..
__global__ void k_cast12(const float* __restrict__ w1, const float* __restrict__ v1,
                         u16* __restrict__ w12) {
  const long i = (long)blockIdx.x * 256 + threadIdx.x;  // over NE*FF*HH/8
  const int k8 = (int)(i & 255);                        // HH/8 = 256
  const long fe = i >> 8;
  const int f = (int)(fe & (FF - 1));
  const int e = (int)(fe >> 12);
  const size_t so = ((size_t)(e * FF + f)) * HH + (size_t)k8 * 8;
  const int cr = ((f >> 4) << 5) + (f & 15);
  u16* d1 = w12 + ((size_t)e * 2 * FF + cr) * HH + (size_t)k8 * 8;
  u16* d2 = d1 + (size_t)16 * HH;
  float4 a = ((const float4*)(w1 + so))[0];
  float4 b = ((const float4*)(w1 + so))[1];
  ((ushort4*)d1)[0] = (ushort4){f2u(a.x), f2u(a.y), f2u(a.z), f2u(a.w)};
  ((ushort4*)d1)[1] = (ushort4){f2u(b.x), f2u(b.y), f2u(b.z), f2u(b.w)};
  a = ((const float4*)(v1 + so))[0];
  b = ((const float4*)(v1 + so))[1];
  ((ushort4*)d2)[0] = (ushort4){f2u(a.x), f2u(a.y), f2u(a.z), f2u(a.w)};
  ((ushort4*)d2)[1] = (ushort4){f2u(b.x), f2u(b.y), f2u(b.z), f2u(b.w)};
}

// w2[e]: [FF][HH] fp32 -> [HH][FF] bf16 transposed
__global__ void k_tcast(const float* __restrict__ w2, u16* __restrict__ dst) {
  const int e = blockIdx.z;
  const float* src = w2 + (size_t)e * FF * HH;
  u16* d = dst + (size_t)e * HH * FF;
  __shared__ float tile[32][33];
  int h0 = blockIdx.x * 32;
  int f0 = blockIdx.y * 32;
  int tx = threadIdx.x, ty = threadIdx.y;
  #pragma unroll
  for (int i = 0; i < 4; ++i)
    tile[ty + i*8][tx] = src[(size_t)(f0 + ty + i*8) * HH + h0 + tx];
  __syncthreads();
  #pragma unroll
  for (int i = 0; i < 4; ++i)
    d[(size_t)(h0 + ty + i*8) * FF + f0 + tx] = f2u(tile[tx][ty + i*8]);
}

// gather x rows into per-expert panels, zero-pad to 256 multiple.
__global__ void k_gather(const u16* __restrict__ xb, const int* __restrict__ tok,
                         const int* __restrict__ cnt, u16* __restrict__ xg) {
  const int e = blockIdx.y;
  const int r = blockIdx.x;
  const int c = cnt[e];
  const int mcap = (c + 255) & ~255;
  if (r >= mcap) return;
  uint4* dst = (uint4*)(xg + ((size_t)e * TT + r) * HH) + threadIdx.x;
  if (r < c) {
    const uint4* src = (const uint4*)(xb + (size_t)tok[e * TT + r] * HH) + threadIdx.x;
    *dst = *src;
  } else {
    *dst = (uint4){0, 0, 0, 0};
  }
}

// 256x256 pipelined bf16 GEMM, BK=64, 8 waves (2Mx4N).
// LDS 160KB: A triple-buffered (3x32KB), B double-buffered (2x32KB).
// A(t+2) staged BEFORE compute(t) (slot freed by compute(t-1)+barrier),
// B(t+2) after; counted vmcnt(8); T2 row-XOR swizzle; setprio on compute.
// MODE 0: GLU  A=xg[e] (K=2048), B=w12[e] (8192 rows), out hc bf16 silu-fused
// MODE 1: down A=hc[e] (K=4096), B=w2t[e] (2048 rows), out dcomp fp32
template<int MODE>
__global__ __launch_bounds__(512)
void gemm256(const u16* __restrict__ Aall, const u16* __restrict__ Ball,
             const int* __restrict__ cnt, void* __restrict__ Oall) {
  constexpr int KD  = (MODE == 0) ? HH : FF;   // 2048 / 4096
  constexpr int NTK = KD / 64;                 // 32 / 64
  constexpr int NT  = (MODE == 0) ? 32 : 8;    // N tiles
  constexpr int NB  = (MODE == 0) ? 2 * FF : HH;

  const int bid = blockIdx.x;
  const int e   = bid / (8 * NT);
  const int rem = bid % (8 * NT);
  const int ntl = rem / 8;        // B tile (outer)
  const int mt  = rem % 8;        // A tile (inner)
  const int c = cnt[e];
  const int mcap = (c + 255) & ~255;
  if (mt * 256 >= mcap) return;

  __shared__ __align__(16) u16 smem[81920];    // 160 KB exactly
  u16* const As = smem;                        // 3 slots x 16384 u16
  u16* const Bs = smem + 49152;                // 2 slots x 16384 u16

  const int tid  = threadIdx.x;
  const int lane = tid & 63;
  const int wave = tid >> 6;
  const int wm = wave >> 2;      // 0..1
  const int wn = wave & 3;       // 0..3

  const u16* A = Aall + (size_t)e * TT * KD + (size_t)(mt * 256) * KD;
  const u16* B = Ball + (size_t)e * NB * KD + (size_t)(ntl * 256) * KD;

  // staging: linear LDS dest, pre-swizzled global source col (rule 21)
  const int srow = tid >> 3;                                   // 0..63
  const int scol = (((tid & 7) ^ ((tid >> 3) & 7)) << 3);      // u16 units
  const u16* Asrc0 = A + (size_t)(0 * 64 + srow) * KD + scol;
  const u16* Asrc1 = A + (size_t)(1 * 64 + srow) * KD + scol;
  const u16* Asrc2 = A + (size_t)(2 * 64 + srow) * KD + scol;
  const u16* Asrc3 = A + (size_t)(3 * 64 + srow) * KD + scol;
  const u16* Bsrc0 = B + (size_t)(0 * 64 + srow) * KD + scol;
  const u16* Bsrc1 = B + (size_t)(1 * 64 + srow) * KD + scol;
  const u16* Bsrc2 = B + (size_t)(2 * 64 + srow) * KD + scol;
  const u16* Bsrc3 = B + (size_t)(3 * 64 + srow) * KD + scol;

  auto stageA = [&](int slot, int kt) {
    const int ko = kt * 64;
    u16* a = As + slot * 16384 + tid * 8;
    gld16(a,         Asrc0 + ko);
    gld16(a + 4096,  Asrc1 + ko);
    gld16(a + 8192,  Asrc2 + ko);
    gld16(a + 12288, Asrc3 + ko);
  };
  auto stageB = [&](int slot, int kt) {
    const int ko = kt * 64;
    u16* b = Bs + slot * 16384 + tid * 8;
    gld16(b,         Bsrc0 + ko);
    gld16(b + 4096,  Bsrc1 + ko);
    gld16(b + 8192,  Bsrc2 + ko);
    gld16(b + 12288, Bsrc3 + ko);
  };

  f32x4 acc[8][4];
  #pragma unroll
  for (int m = 0; m < 8; ++m)
    #pragma unroll
    for (int n = 0; n < 4; ++n)
      acc[m][n] = (f32x4){0.f, 0.f, 0.f, 0.f};

  const int lr = lane & 15;
  // swizzled col part per ks (u16 units): (ks*32 + (lane>>4)*8) ^ ((lane&7)*8)
  const int cs0 = ((0 << 5) + (((lane >> 4) & 3) << 3)) ^ ((lane & 7) << 3);
  const int cs1 = ((1 << 5) + (((lane >> 4) & 3) << 3)) ^ ((lane & 7) << 3);

  // monolithic compute: compiler-scheduled ds_read/MFMA interleave (R3-proven)
  auto compute = [&](const u16* ab, const u16* bb) {
    __builtin_amdgcn_s_setprio(1);
    #pragma unroll
    for (int ks = 0; ks < 2; ++ks) {
      const int cpp = ks ? cs1 : cs0;
      bf16x8 bf[4];
      #pragma unroll
      for (int n = 0; n < 4; ++n) {
        const int row = wn * 64 + n * 16 + lr;
        bf[n] = *(const bf16x8*)(bb + (row << 6) + cpp);
      }
      #pragma unroll
      for (int m = 0; m < 8; ++m) {
        const int row = wm * 128 + m * 16 + lr;
        bf16x8 af = *(const bf16x8*)(ab + (row << 6) + cpp);
        #pragma unroll
        for (int n = 0; n < 4; ++n)
          acc[m][n] = __builtin_amdgcn_mfma_f32_16x16x32_bf16(af, bf[n], acc[m][n], 0, 0, 0);
      }
    }
    __builtin_amdgcn_s_setprio(0);
  };

  // prologue: 2 K-tiles staged
  stageA(0, 0); stageB(0, 0);
  stageA(1, 1); stageB(1, 1);

  int ca = 0;  // A slot holding K-tile t
  for (int t = 0; t < NTK; ++t) {
    if (t == NTK - 1) { asm volatile("s_waitcnt vmcnt(0)" ::: "memory"); }
    else              { asm volatile("s_waitcnt vmcnt(8)" ::: "memory"); }
    __builtin_amdgcn_s_barrier();
    __builtin_amdgcn_sched_barrier(0);
    const int bslot = t & 1;
    // A(t+2) -> slot (ca+2)%3, freed by compute(t-1) (all waves past barrier)
    const int ca2 = (ca == 0) ? 2 : ca - 1;
    if (t + 2 < NTK) stageA(ca2, t + 2);
    compute(As + ca * 16384, Bs + bslot * 16384);
    __builtin_amdgcn_s_barrier();
    // B(t+2) -> slot t&1, freed by compute(t) (all waves past barrier)
    if (t + 2 < NTK) stageB(bslot, t + 2);
    ca = (ca == 2) ? 0 : ca + 1;
  }

  // C/D: col = lane&15, row = (lane>>4)*4 + j  (verified)
  const int rb = mt * 256 + wm * 128 + ((lane >> 4) << 2);
  if (MODE == 0) {
    u16* H = (u16*)Oall + (size_t)e * TT * FF;
    const int fb = ntl * 128 + wn * 32 + lr;
    #pragma unroll
    for (int m = 0; m < 8; ++m)
      #pragma unroll
      for (int np = 0; np < 2; ++np)
        #pragma unroll
        for (int j = 0; j < 4; ++j) {
          float g = acc[m][2*np][j];
          float u = acc[m][2*np + 1][j];
          float hh = (g / (1.f + __expf(-g))) * u;
          H[(size_t)(rb + m*16 + j) * FF + fb + np*16] = f2u(hh);
        }
  } else {
    float* D = (float*)Oall + (size_t)e * TT * HH;
    const int cb = ntl * 256 + wn * 64 + lr;
    #pragma unroll
    for (int m = 0; m < 8; ++m)
      #pragma unroll
      for (int n = 0; n < 4; ++n)
        #pragma unroll
        for (int j = 0; j < 4; ++j)
          D[(size_t)(rb + m*16 + j) * HH + cb + n*16] = acc[m][n][j];
  }
}

__global__ void k_combine(const float* __restrict__ tw, const int* __restrict__ te,
                          const int* __restrict__ posmap, const float* __restrict__ dcomp,
                          float* __restrict__ out) {
  const int t = blockIdx.x;
  const int c0 = threadIdx.x * 8;
  float a[8] = {0.f, 0.f, 0.f, 0.f, 0.f, 0.f, 0.f, 0.f};
  #pragma unroll
  for (int k = 0; k < KTOP; ++k) {
    const int e = te[t * KTOP + k];
    const float w = tw[t * KTOP + k];
    const int r = posmap[t * NE + e];
    const float* row = dcomp + ((size_t)e * TT + r) * HH + c0;
    const float4 p = ((const float4*)row)[0];
    const float4 q = ((const float4*)row)[1];
    a[0] += w * p.x; a[1] += w * p.y; a[2] += w * p.z; a[3] += w * p.w;
    a[4] += w * q.x; a[5] += w * q.y; a[6] += w * q.z; a[7] += w * q.w;
  }
  float* o = out + (size_t)t * HH + c0;
  ((float4*)o)[0] = (float4){a[0], a[1], a[2], a[3]};
  ((float4*)o)[1] = (float4){a[4], a[5], a[6], a[7]};
}

extern "C" void kernel_launch(void* const* d_in, const int* in_sizes, int n_in,
                              void* d_out, int out_size, void* d_ws, size_t ws_size,
                              hipStream_t stream) {
  const float* x  = (const float*)d_in[0];
  const float* tw = (const float*)d_in[2];
  const int*   te = (const int*)d_in[3];
  const float* w1 = (const float*)d_in[4];
  const float* v1 = (const float*)d_in[5];
  const float* w2 = (const float*)d_in[6];
  float* out = (float*)d_out;

  char* p = (char*)d_ws;
  int*   cnt    = (int*)p;   p += 256;
  int*   tok    = (int*)p;   p += (size_t)NE * TT * 4;
  int*   posmap = (int*)p;   p += (size_t)TT * NE * 4;
  u16*   xb     = (u16*)p;   p += (size_t)TT * HH * 2;            // 8 MB
  u16*   xg     = (u16*)p;   p += (size_t)NE * TT * HH * 2;       // 64 MB
  u16*   w12b   = (u16*)p;   p += (size_t)NE * 2 * FF * HH * 2;   // 268 MB
  u16*   w2tb   = (u16*)p;   p += (size_t)NE * HH * FF * 2;       // 134 MB
  u16*   hc     = (u16*)p;   p += (size_t)NE * TT * FF * 2;       // 134 MB
  float* dcomp  = (float*)p; p += (size_t)NE * TT * HH * 4;       // 134 MB

  k_build<<<NE, 256, 0, stream>>>(te, cnt, tok, posmap);
  k_cast4<<<1024, 256, 0, stream>>>((const float4*)x, (ushort4*)xb, TT * HH / 4);
  k_cast12<<<NE * FF * (HH / 8) / 256, 256, 0, stream>>>(w1, v1, w12b);
  k_tcast<<<dim3(HH / 32, FF / 32, NE), dim3(32, 8), 0, stream>>>(w2, w2tb);
  k_gather<<<dim3(TT, NE), 256, 0, stream>>>(xb, tok, cnt, xg);

  // GLU: 8 e x 32 ntl x 8 mt = 2048 blocks
  gemm256<0><<<2048, 512, 0, stream>>>(xg, w12b, cnt, hc);
  // down: 8 e x 8 ntl x 8 mt = 512 blocks
  gemm256<1><<<512, 512, 0, stream>>>(hc, w2tb, cnt, dcomp);
  k_combine<<<TT, 256, 0, stream>>>(tw, te, posmap, dcomp, out);
}

// Round 6
// 680.839 us; speedup vs baseline: 1.5359x; 1.4556x over previous
//
#include <hip/hip_runtime.h>
#include <hip/hip_bf16.h>

#define NE 8
#define FF 4096
#define HH 2048
#define TT 2048
#define KTOP 4

typedef unsigned short u16;
typedef __attribute__((ext_vector_type(8))) short bf16x8;
typedef __attribute__((ext_vector_type(4))) float f32x4;

__device__ __forceinline__ u16 f2u(float f) {
  __hip_bfloat16 b = __float2bfloat16(f);
  return *reinterpret_cast<u16*>(&b);
}

__device__ __forceinline__ void gld16(void* lds, const void* g) {
  __builtin_amdgcn_global_load_lds(
      (const __attribute__((address_space(1))) void*)g,
      (__attribute__((address_space(3))) void*)lds, 16, 0, 0);
}

// Per-expert token lists, deterministic (token ascending).
__global__ void k_build(const int* __restrict__ te, int* __restrict__ cnt,
                        int* __restrict__ tok, int* __restrict__ posmap) {
  const int e = blockIdx.x;
  const int tl = threadIdx.x;          // 256 threads, 8 tokens each
  const int base = tl * 8;
  int mem[8];
  int my = 0;
  #pragma unroll
  for (int i = 0; i < 8; ++i) {
    const int t = base + i;
    bool m = false;
    #pragma unroll
    for (int k = 0; k < KTOP; ++k) m |= (te[t * KTOP + k] == e);
    mem[i] = m ? 1 : 0;
    my += mem[i];
  }
  __shared__ int s[256];
  s[tl] = my;
  __syncthreads();
  for (int off = 1; off < 256; off <<= 1) {
    int v = (tl >= off) ? s[tl - off] : 0;
    __syncthreads();
    s[tl] += v;
    __syncthreads();
  }
  int r = s[tl] - my;
  if (tl == 255) cnt[e] = s[255];
  #pragma unroll
  for (int i = 0; i < 8; ++i) {
    if (mem[i]) {
      const int t = base + i;
      tok[e * TT + r] = t;
      posmap[t * NE + e] = r;
      ++r;
    }
  }
}

__global__ void k_cast4(const float4* __restrict__ src, ushort4* __restrict__ dst, int n4) {
  int stride = gridDim.x * blockDim.x;
  for (int i = blockIdx.x * blockDim.x + threadIdx.x; i < n4; i += stride) {
    float4 f = src[i];
    ushort4 o;
    o.x = f2u(f.x); o.y = f2u(f.y); o.z = f2u(f.z); o.w = f2u(f.w);
    dst[i] = o;
  }
}

// w1,v1 -> combined w12[e][8192][HH] bf16, 16-row interleave:
// w12 rows 32j..32j+15 = w1 rows 16j.., rows 32j+16..32j+31 = v1 rows 16j..
__global__ void k_cast12(const float* __restrict__ w1, const float* __restrict__ v1,
                         u16* __restrict__ w12) {
  const long i = (long)blockIdx.x * 256 + threadIdx.x;  // over NE*FF*HH/8
  const int k8 = (int)(i & 255);                        // HH/8 = 256
  const long fe = i >> 8;
  const int f = (int)(fe & (FF - 1));
  const int e = (int)(fe >> 12);
  const size_t so = ((size_t)(e * FF + f)) * HH + (size_t)k8 * 8;
  const int cr = ((f >> 4) << 5) + (f & 15);
  u16* d1 = w12 + ((size_t)e * 2 * FF + cr) * HH + (size_t)k8 * 8;
  u16* d2 = d1 + (size_t)16 * HH;
  float4 a = ((const float4*)(w1 + so))[0];
  float4 b = ((const float4*)(w1 + so))[1];
  ((ushort4*)d1)[0] = (ushort4){f2u(a.x), f2u(a.y), f2u(a.z), f2u(a.w)};
  ((ushort4*)d1)[1] = (ushort4){f2u(b.x), f2u(b.y), f2u(b.z), f2u(b.w)};
  a = ((const float4*)(v1 + so))[0];
  b = ((const float4*)(v1 + so))[1];
  ((ushort4*)d2)[0] = (ushort4){f2u(a.x), f2u(a.y), f2u(a.z), f2u(a.w)};
  ((ushort4*)d2)[1] = (ushort4){f2u(b.x), f2u(b.y), f2u(b.z), f2u(b.w)};
}

// w2[e]: [FF][HH] fp32 -> [HH][FF] bf16 transposed
__global__ void k_tcast(const float* __restrict__ w2, u16* __restrict__ dst) {
  const int e = blockIdx.z;
  const float* src = w2 + (size_t)e * FF * HH;
  u16* d = dst + (size_t)e * HH * FF;
  __shared__ float tile[32][33];
  int h0 = blockIdx.x * 32;
  int f0 = blockIdx.y * 32;
  int tx = threadIdx.x, ty = threadIdx.y;
  #pragma unroll
  for (int i = 0; i < 4; ++i)
    tile[ty + i*8][tx] = src[(size_t)(f0 + ty + i*8) * HH + h0 + tx];
  __syncthreads();
  #pragma unroll
  for (int i = 0; i < 4; ++i)
    d[(size_t)(h0 + ty + i*8) * FF + f0 + tx] = f2u(tile[tx][ty + i*8]);
}

// gather x rows into per-expert panels, zero-pad to 256 multiple.
__global__ void k_gather(const u16* __restrict__ xb, const int* __restrict__ tok,
                         const int* __restrict__ cnt, u16* __restrict__ xg) {
  const int e = blockIdx.y;
  const int r = blockIdx.x;
  const int c = cnt[e];
  const int mcap = (c + 255) & ~255;
  if (r >= mcap) return;
  uint4* dst = (uint4*)(xg + ((size_t)e * TT + r) * HH) + threadIdx.x;
  if (r < c) {
    const uint4* src = (const uint4*)(xb + (size_t)tok[e * TT + r] * HH) + threadIdx.x;
    *dst = *src;
  } else {
    *dst = (uint4){0, 0, 0, 0};
  }
}

// 256x256 bf16 GEMM, BK=64, 8 waves (2Mx4N), m201-style 8-phase schedule.
// LDS 128KB = [A|B][dbuf][ks][256 rows][32 cols] (K-half-blocked: each 16KB
// half-tile contiguous = 2 gld_lds; frag reads bank-conflict-free, no swizzle).
// 4 phases per K-tile (ks,mq), B-frags carried across the mq pair.
// Counted vmcnt(6) (= 2 loads x 3 half-tiles in flight) twice per K-tile.
// Block order: R3's XCD-aware swz (bid stride-8 = same XCD => L2 A-panel reuse).
// MODE 0: GLU  A=xg[e] (K=2048), B=w12[e] (8192 rows), out hc bf16 silu-fused
// MODE 1: down A=hc[e] (K=4096), B=w2t[e] (2048 rows), out dcomp fp32
template<int MODE>
__global__ __launch_bounds__(512)
void gemm256(const u16* __restrict__ Aall, const u16* __restrict__ Ball,
             const int* __restrict__ cnt, void* __restrict__ Oall) {
  constexpr int KD  = (MODE == 0) ? HH : FF;   // 2048 / 4096
  constexpr int NTK = KD / 64;                 // 32 / 64 K-tiles
  constexpr int NT  = (MODE == 0) ? 32 : 8;    // N tiles
  constexpr int NB  = (MODE == 0) ? 2 * FF : HH;

  const int nwg = gridDim.x;
  const int bid = blockIdx.x;
  const int swz = (bid & 7) * (nwg >> 3) + (bid >> 3);
  const int e   = swz / (8 * NT);
  const int rem = swz % (8 * NT);
  const int mt  = rem / NT;
  const int ntl = rem % NT;
  const int c = cnt[e];
  const int mcap = (c + 255) & ~255;
  if (mt * 256 >= mcap) return;

  __shared__ __align__(16) u16 smem[65536];    // 128 KB
  // A block(d,ks) = smem + (d*2+ks)*8192 ; B block = smem + 32768 + (d*2+ks)*8192

  const int tid  = threadIdx.x;
  const int lane = tid & 63;
  const int wave = tid >> 6;
  const int wm = wave >> 2;      // 0..1
  const int wn = wave & 3;       // 0..3

  const u16* A = Aall + (size_t)e * TT * KD + (size_t)(mt * 256) * KD;
  const u16* B = Ball + (size_t)e * NB * KD + (size_t)(ntl * 256) * KD;

  // staging: thread covers LDS u16 q = g*4096 + tid*8 of a 16KB half-tile
  // -> row = g*128 + tid/4, col = (tid&3)*8 (linear dest == linear source)
  const int tq = tid >> 2;
  const int tc = (tid & 3) * 8;
  const u16* pA = A + (size_t)tq * KD + tc;
  const u16* pB = B + (size_t)tq * KD + tc;

  auto stage = [&](int op, int d, int ks, int kt) {
    u16* dst = smem + (op ? 32768 : 0) + ((d * 2 + ks) << 13) + tid * 8;
    const u16* src = (op ? pB : pA) + kt * 64 + ks * 32;
    gld16(dst,        src);
    gld16(dst + 4096, src + (size_t)128 * KD);
  };

  f32x4 acc[8][4];
  #pragma unroll
  for (int m = 0; m < 8; ++m)
    #pragma unroll
    for (int n = 0; n < 4; ++n)
      acc[m][n] = (f32x4){0.f, 0.f, 0.f, 0.f};

  const int lr = lane & 15;
  const int lc = ((lane >> 4) & 3) * 8;

  bf16x8 af[4], bf[4];

  auto rdA = [&](int d, int ks, int mq) {
    const u16* blk = smem + ((d * 2 + ks) << 13);
    #pragma unroll
    for (int m = 0; m < 4; ++m)
      af[m] = *(const bf16x8*)(blk + (wm * 128 + mq * 64 + m * 16 + lr) * 32 + lc);
  };
  auto rdB = [&](int d, int ks) {
    const u16* blk = smem + 32768 + ((d * 2 + ks) << 13);
    #pragma unroll
    for (int n = 0; n < 4; ++n)
      bf[n] = *(const bf16x8*)(blk + (wn * 64 + n * 16 + lr) * 32 + lc);
  };
  auto vmwait = [&](int n) {
    switch (n) {
      case 0: asm volatile("s_waitcnt vmcnt(0)" ::: "memory"); break;
      case 2: asm volatile("s_waitcnt vmcnt(2)" ::: "memory"); break;
      case 4: asm volatile("s_waitcnt vmcnt(4)" ::: "memory"); break;
      default: asm volatile("s_waitcnt vmcnt(6)" ::: "memory"); break;
    }
  };

  // phase: {ds_read frags, stage 1 half-tile} -> barrier -> lgkm(0) ->
  //        16 MFMA (setprio) -> [vmcnt] -> barrier
  auto phase = [&](int d, int ks, int mq, bool ldB,
                   int stOp, int stD, int stKs, int stKt, int vm) {
    if (ldB) rdB(d, ks);
    rdA(d, ks, mq);
    if (stKt < NTK) stage(stOp, stD, stKs, stKt);
    __builtin_amdgcn_s_barrier();
    asm volatile("s_waitcnt lgkmcnt(0)" ::: "memory");
    __builtin_amdgcn_sched_barrier(0);
    __builtin_amdgcn_s_setprio(1);
    #pragma unroll
    for (int m = 0; m < 4; ++m)
      #pragma unroll
      for (int n = 0; n < 4; ++n)
        acc[mq * 4 + m][n] = __builtin_amdgcn_mfma_f32_16x16x32_bf16(
            af[m], bf[n], acc[mq * 4 + m][n], 0, 0, 0);
    __builtin_amdgcn_s_setprio(0);
    if (vm >= 0) vmwait(vm);
    __builtin_amdgcn_s_barrier();
  };

  // prologue: stage half-tiles h0..h4 (in stream order), wait first K-tile's
  // first halves (vmcnt(6): 10 outstanding -> h0,h1 landed), barrier.
  stage(0, 0, 0, 0);  // h0: A ks0 (t0)
  stage(1, 0, 0, 0);  // h1: B ks0 (t0)
  stage(0, 0, 1, 0);  // h2: A ks1 (t0)
  stage(1, 0, 1, 0);  // h3: B ks1 (t0)
  stage(0, 1, 0, 1);  // h4: A ks0 (t1)
  vmwait(6);
  __builtin_amdgcn_s_barrier();

  for (int i = 0; i < NTK / 2; ++i) {
    const int t0 = 2 * i, t1 = 2 * i + 1;
    // vmcnt tail drain: vmP1(t)=2*clamp(4NTK-4t-4,0,3), vmP3(t)=2*clamp(4NTK-4t-6,0,3)
    int v;
    int v1a = 4 * NTK - 4 * t0 - 4; v1a = v1a > 3 ? 3 : (v1a < 0 ? 0 : v1a); v1a *= 2;
    int v3a = 4 * NTK - 4 * t0 - 6; v3a = v3a > 3 ? 3 : (v3a < 0 ? 0 : v3a); v3a *= 2;
    int v1b = 4 * NTK - 4 * t1 - 4; v1b = v1b > 3 ? 3 : (v1b < 0 ? 0 : v1b); v1b *= 2;
    int v3b = 4 * NTK - 4 * t1 - 6; v3b = v3b > 3 ? 3 : (v3b < 0 ? 0 : v3b); v3b *= 2;
    (void)v;
    // K-tile t0 (dbuf 0); stages h=4*t0+5..8 in order
    phase(0, 0, 0, true,  1, 1, 0, t0 + 1, -1);   // P0: reads A[ks0,mq0]+B[ks0]; stage B-ks0(t0+1)->d1
    phase(0, 0, 1, false, 0, 1, 1, t0 + 1, v1a);  // P1: A[ks0,mq1];            stage A-ks1(t0+1)->d1
    phase(0, 1, 0, true,  1, 1, 1, t0 + 1, -1);   // P2: A[ks1,mq0]+B[ks1];     stage B-ks1(t0+1)->d1
    phase(0, 1, 1, false, 0, 0, 0, t0 + 2, v3a);  // P3: A[ks1,mq1];            stage A-ks0(t0+2)->d0
    // K-tile t1 (dbuf 1); stages h=4*t1+5..8
    phase(1, 0, 0, true,  1, 0, 0, t1 + 1, -1);
    phase(1, 0, 1, false, 0, 0, 1, t1 + 1, v1b);
    phase(1, 1, 0, true,  1, 0, 1, t1 + 1, -1);
    phase(1, 1, 1, false, 0, 1, 0, t1 + 2, v3b);  // t1+2 odd -> d1
  }

  // C/D: col = lane&15, row = (lane>>4)*4 + j  (verified)
  const int rb = mt * 256 + wm * 128 + ((lane >> 4) << 2);
  if (MODE == 0) {
    u16* H = (u16*)Oall + (size_t)e * TT * FF;
    const int fb = ntl * 128 + wn * 32 + lr;
    #pragma unroll
    for (int m = 0; m < 8; ++m)
      #pragma unroll
      for (int np = 0; np < 2; ++np)
        #pragma unroll
        for (int j = 0; j < 4; ++j) {
          float g = acc[m][2*np][j];
          float u = acc[m][2*np + 1][j];
          float hh = (g / (1.f + __expf(-g))) * u;
          H[(size_t)(rb + m*16 + j) * FF + fb + np*16] = f2u(hh);
        }
  } else {
    float* D = (float*)Oall + (size_t)e * TT * HH;
    const int cb = ntl * 256 + wn * 64 + lr;
    #pragma unroll
    for (int m = 0; m < 8; ++m)
      #pragma unroll
      for (int n = 0; n < 4; ++n)
        #pragma unroll
        for (int j = 0; j < 4; ++j)
          D[(size_t)(rb + m*16 + j) * HH + cb + n*16] = acc[m][n][j];
  }
}

__global__ void k_combine(const float* __restrict__ tw, const int* __restrict__ te,
                          const int* __restrict__ posmap, const float* __restrict__ dcomp,
                          float* __restrict__ out) {
  const int t = blockIdx.x;
  const int c0 = threadIdx.x * 8;
  float a[8] = {0.f, 0.f, 0.f, 0.f, 0.f, 0.f, 0.f, 0.f};
  #pragma unroll
  for (int k = 0; k < KTOP; ++k) {
    const int e = te[t * KTOP + k];
    const float w = tw[t * KTOP + k];
    const int r = posmap[t * NE + e];
    const float* row = dcomp + ((size_t)e * TT + r) * HH + c0;
    const float4 p = ((const float4*)row)[0];
    const float4 q = ((const float4*)row)[1];
    a[0] += w * p.x; a[1] += w * p.y; a[2] += w * p.z; a[3] += w * p.w;
    a[4] += w * q.x; a[5] += w * q.y; a[6] += w * q.z; a[7] += w * q.w;
  }
  float* o = out + (size_t)t * HH + c0;
  ((float4*)o)[0] = (float4){a[0], a[1], a[2], a[3]};
  ((float4*)o)[1] = (float4){a[4], a[5], a[6], a[7]};
}

extern "C" void kernel_launch(void* const* d_in, const int* in_sizes, int n_in,
                              void* d_out, int out_size, void* d_ws, size_t ws_size,
                              hipStream_t stream) {
  const float* x  = (const float*)d_in[0];
  const float* tw = (const float*)d_in[2];
  const int*   te = (const int*)d_in[3];
  const float* w1 = (const float*)d_in[4];
  const float* v1 = (const float*)d_in[5];
  const float* w2 = (const float*)d_in[6];
  float* out = (float*)d_out;

  char* p = (char*)d_ws;
  int*   cnt    = (int*)p;   p += 256;
  int*   tok    = (int*)p;   p += (size_t)NE * TT * 4;
  int*   posmap = (int*)p;   p += (size_t)TT * NE * 4;
  u16*   xb     = (u16*)p;   p += (size_t)TT * HH * 2;            // 8 MB
  u16*   xg     = (u16*)p;   p += (size_t)NE * TT * HH * 2;       // 64 MB
  u16*   w12b   = (u16*)p;   p += (size_t)NE * 2 * FF * HH * 2;   // 268 MB
  u16*   w2tb   = (u16*)p;   p += (size_t)NE * HH * FF * 2;       // 134 MB
  u16*   hc     = (u16*)p;   p += (size_t)NE * TT * FF * 2;       // 134 MB
  float* dcomp  = (float*)p; p += (size_t)NE * TT * HH * 4;       // 134 MB

  k_build<<<NE, 256, 0, stream>>>(te, cnt, tok, posmap);
  k_cast4<<<1024, 256, 0, stream>>>((const float4*)x, (ushort4*)xb, TT * HH / 4);
  k_cast12<<<NE * FF * (HH / 8) / 256, 256, 0, stream>>>(w1, v1, w12b);
  k_tcast<<<dim3(HH / 32, FF / 32, NE), dim3(32, 8), 0, stream>>>(w2, w2tb);
  k_gather<<<dim3(TT, NE), 256, 0, stream>>>(xb, tok, cnt, xg);

  // GLU: 8 e x 8 mt x 32 ntl = 2048 blocks
  gemm256<0><<<2048, 512, 0, stream>>>(xg, w12b, cnt, hc);
  // down: 8 e x 8 mt x 8 ntl = 512 blocks
  gemm256<1><<<512, 512, 0, stream>>>(hc, w2tb, cnt, dcomp);
  k_combine<<<TT, 256, 0, stream>>>(tw, te, posmap, dcomp, out);
}

// Round 7
// 617.900 us; speedup vs baseline: 1.6924x; 1.1019x over previous
//
#include <hip/hip_runtime.h>
#include <hip/hip_bf16.h>

#define NE 8
#define FF 4096
#define HH 2048
#define TT 2048
#define KTOP 4

typedef unsigned short u16;
typedef __attribute__((ext_vector_type(8))) short bf16x8;
typedef __attribute__((ext_vector_type(4))) float f32x4;

__device__ __forceinline__ u16 f2u(float f) {
  __hip_bfloat16 b = __float2bfloat16(f);
  return *reinterpret_cast<u16*>(&b);
}

__device__ __forceinline__ void gld16(void* lds, const void* g) {
  __builtin_amdgcn_global_load_lds(
      (const __attribute__((address_space(1))) void*)g,
      (__attribute__((address_space(3))) void*)lds, 16, 0, 0);
}

// Per-expert token lists, deterministic (token ascending).
__global__ void k_build(const int* __restrict__ te, int* __restrict__ cnt,
                        int* __restrict__ tok, int* __restrict__ posmap) {
  const int e = blockIdx.x;
  const int tl = threadIdx.x;          // 256 threads, 8 tokens each
  const int base = tl * 8;
  int mem[8];
  int my = 0;
  #pragma unroll
  for (int i = 0; i < 8; ++i) {
    const int t = base + i;
    bool m = false;
    #pragma unroll
    for (int k = 0; k < KTOP; ++k) m |= (te[t * KTOP + k] == e);
    mem[i] = m ? 1 : 0;
    my += mem[i];
  }
  __shared__ int s[256];
  s[tl] = my;
  __syncthreads();
  for (int off = 1; off < 256; off <<= 1) {
    int v = (tl >= off) ? s[tl - off] : 0;
    __syncthreads();
    s[tl] += v;
    __syncthreads();
  }
  int r = s[tl] - my;
  if (tl == 255) cnt[e] = s[255];
  #pragma unroll
  for (int i = 0; i < 8; ++i) {
    if (mem[i]) {
      const int t = base + i;
      tok[e * TT + r] = t;
      posmap[t * NE + e] = r;
      ++r;
    }
  }
}

__global__ void k_cast4(const float4* __restrict__ src, ushort4* __restrict__ dst, int n4) {
  int stride = gridDim.x * blockDim.x;
  for (int i = blockIdx.x * blockDim.x + threadIdx.x; i < n4; i += stride) {
    float4 f = src[i];
    ushort4 o;
    o.x = f2u(f.x); o.y = f2u(f.y); o.z = f2u(f.z); o.w = f2u(f.w);
    dst[i] = o;
  }
}

// w1,v1 -> combined w12[e][8192][HH] bf16, 16-row interleave:
// w12 rows 32j..32j+15 = w1 rows 16j.., rows 32j+16..32j+31 = v1 rows 16j..
__global__ void k_cast12(const float* __restrict__ w1, const float* __restrict__ v1,
                         u16* __restrict__ w12) {
  const long i = (long)blockIdx.x * 256 + threadIdx.x;  // over NE*FF*HH/8
  const int k8 = (int)(i & 255);                        // HH/8 = 256
  const long fe = i >> 8;
  const int f = (int)(fe & (FF - 1));
  const int e = (int)(fe >> 12);
  const size_t so = ((size_t)(e * FF + f)) * HH + (size_t)k8 * 8;
  const int cr = ((f >> 4) << 5) + (f & 15);
  u16* d1 = w12 + ((size_t)e * 2 * FF + cr) * HH + (size_t)k8 * 8;
  u16* d2 = d1 + (size_t)16 * HH;
  float4 a = ((const float4*)(w1 + so))[0];
  float4 b = ((const float4*)(w1 + so))[1];
  ((ushort4*)d1)[0] = (ushort4){f2u(a.x), f2u(a.y), f2u(a.z), f2u(a.w)};
  ((ushort4*)d1)[1] = (ushort4){f2u(b.x), f2u(b.y), f2u(b.z), f2u(b.w)};
  a = ((const float4*)(v1 + so))[0];
  b = ((const float4*)(v1 + so))[1];
  ((ushort4*)d2)[0] = (ushort4){f2u(a.x), f2u(a.y), f2u(a.z), f2u(a.w)};
  ((ushort4*)d2)[1] = (ushort4){f2u(b.x), f2u(b.y), f2u(b.z), f2u(b.w)};
}

// w2[e]: [FF][HH] fp32 -> [HH][FF] bf16 transposed
__global__ void k_tcast(const float* __restrict__ w2, u16* __restrict__ dst) {
  const int e = blockIdx.z;
  const float* src = w2 + (size_t)e * FF * HH;
  u16* d = dst + (size_t)e * HH * FF;
  __shared__ float tile[32][33];
  int h0 = blockIdx.x * 32;
  int f0 = blockIdx.y * 32;
  int tx = threadIdx.x, ty = threadIdx.y;
  #pragma unroll
  for (int i = 0; i < 4; ++i)
    tile[ty + i*8][tx] = src[(size_t)(f0 + ty + i*8) * HH + h0 + tx];
  __syncthreads();
  #pragma unroll
  for (int i = 0; i < 4; ++i)
    d[(size_t)(h0 + ty + i*8) * FF + f0 + tx] = f2u(tile[tx][ty + i*8]);
}

// gather x rows into per-expert panels, zero-pad to 256 multiple.
__global__ void k_gather(const u16* __restrict__ xb, const int* __restrict__ tok,
                         const int* __restrict__ cnt, u16* __restrict__ xg) {
  const int e = blockIdx.y;
  const int r = blockIdx.x;
  const int c = cnt[e];
  const int mcap = (c + 255) & ~255;
  if (r >= mcap) return;
  uint4* dst = (uint4*)(xg + ((size_t)e * TT + r) * HH) + threadIdx.x;
  if (r < c) {
    const uint4* src = (const uint4*)(xb + (size_t)tok[e * TT + r] * HH) + threadIdx.x;
    *dst = *src;
  } else {
    *dst = (uint4){0, 0, 0, 0};
  }
}

// 256x256 bf16 GEMM, BK=64, 8 waves (2Mx4N), 8-phase schedule + counted vmcnt.
// LDS 128KB = [A|B][dbuf][ks][256 rows][32 cols] (each 16KB half-tile = 2 gld_lds).
// Granule swizzle: logical 16B-granule g of row r stored at physical g^((r>>1)&3)
// (linear LDS dest; inverse-swizzled GLOBAL source col; swizzled ds_read col).
// Block order: bid->swz stride-8 (same-XCD blocks consecutive), decode mt-INNER
// so 8 same-XCD neighbors share one 1MB B panel (L2-resident); A absorbed by LLC.
// MODE 0: GLU  A=xg[e] (K=2048), B=w12[e] (8192 rows), out hc bf16 silu-fused
// MODE 1: down A=hc[e] (K=4096), B=w2t[e] (2048 rows), out dcomp fp32
template<int MODE>
__global__ __launch_bounds__(512)
void gemm256(const u16* __restrict__ Aall, const u16* __restrict__ Ball,
             const int* __restrict__ cnt, void* __restrict__ Oall) {
  constexpr int KD  = (MODE == 0) ? HH : FF;   // 2048 / 4096
  constexpr int NTK = KD / 64;                 // 32 / 64 K-tiles
  constexpr int NT  = (MODE == 0) ? 32 : 8;    // N tiles
  constexpr int NB  = (MODE == 0) ? 2 * FF : HH;

  const int nwg = gridDim.x;
  const int bid = blockIdx.x;
  const int swz = (bid & 7) * (nwg >> 3) + (bid >> 3);
  const int e   = swz / (8 * NT);
  const int rem = swz % (8 * NT);
  const int ntl = rem / 8;        // B tile (outer)
  const int mt  = rem % 8;        // A tile (inner: same-XCD neighbors share B)
  const int c = cnt[e];
  const int mcap = (c + 255) & ~255;
  if (mt * 256 >= mcap) return;

  __shared__ __align__(16) u16 smem[65536];    // 128 KB
  // A block(d,ks) = smem + (d*2+ks)*8192 ; B block = smem + 32768 + (d*2+ks)*8192

  const int tid  = threadIdx.x;
  const int lane = tid & 63;
  const int wave = tid >> 6;
  const int wm = wave >> 2;      // 0..1
  const int wn = wave & 3;       // 0..3

  const u16* A = Aall + (size_t)e * TT * KD + (size_t)(mt * 256) * KD;
  const u16* B = Ball + (size_t)e * NB * KD + (size_t)(ntl * 256) * KD;

  // staging: thread tid writes physical granule (tid&3) of rows tq, tq+128.
  // physical granule p holds logical granule p ^ ((row>>1)&3); row bits 1..2
  // = tq bits 1..2 = tid bits 3..4 (unchanged by +128) -> source col:
  const int tq = tid >> 2;
  const int tc = (((tid & 3) ^ ((tid >> 3) & 3)) << 3);   // u16 units
  const u16* pA = A + (size_t)tq * KD + tc;
  const u16* pB = B + (size_t)tq * KD + tc;

  auto stage = [&](int op, int d, int ks, int kt) {
    u16* dst = smem + (op ? 32768 : 0) + ((d * 2 + ks) << 13) + tid * 8;
    const u16* src = (op ? pB : pA) + kt * 64 + ks * 32;
    gld16(dst,        src);
    gld16(dst + 4096, src + (size_t)128 * KD);
  };

  f32x4 acc[8][4];
  #pragma unroll
  for (int m = 0; m < 8; ++m)
    #pragma unroll
    for (int n = 0; n < 4; ++n)
      acc[m][n] = (f32x4){0.f, 0.f, 0.f, 0.f};

  const int lr = lane & 15;
  // read col: logical granule (lane>>4)&3 at row r (bits 1..2 = lane bits 1..2)
  // -> physical granule ((lane>>4)&3) ^ ((lane>>1)&3); lane-constant.
  const int lc = ((((lane >> 4) & 3) ^ ((lane >> 1) & 3)) << 3);

  bf16x8 af[4], bf[4];

  auto rdA = [&](int d, int ks, int mq) {
    const u16* blk = smem + ((d * 2 + ks) << 13);
    #pragma unroll
    for (int m = 0; m < 4; ++m)
      af[m] = *(const bf16x8*)(blk + (wm * 128 + mq * 64 + m * 16 + lr) * 32 + lc);
  };
  auto rdB = [&](int d, int ks) {
    const u16* blk = smem + 32768 + ((d * 2 + ks) << 13);
    #pragma unroll
    for (int n = 0; n < 4; ++n)
      bf[n] = *(const bf16x8*)(blk + (wn * 64 + n * 16 + lr) * 32 + lc);
  };
  auto vmwait = [&](int n) {
    switch (n) {
      case 0: asm volatile("s_waitcnt vmcnt(0)" ::: "memory"); break;
      case 2: asm volatile("s_waitcnt vmcnt(2)" ::: "memory"); break;
      case 4: asm volatile("s_waitcnt vmcnt(4)" ::: "memory"); break;
      default: asm volatile("s_waitcnt vmcnt(6)" ::: "memory"); break;
    }
  };

  // phase: {ds_read frags, stage 1 half-tile} -> barrier -> lgkm(0) ->
  //        16 MFMA (setprio) -> [vmcnt] -> barrier
  auto phase = [&](int d, int ks, int mq, bool ldB,
                   int stOp, int stD, int stKs, int stKt, int vm) {
    if (ldB) rdB(d, ks);
    rdA(d, ks, mq);
    if (stKt < NTK) stage(stOp, stD, stKs, stKt);
    __builtin_amdgcn_s_barrier();
    asm volatile("s_waitcnt lgkmcnt(0)" ::: "memory");
    __builtin_amdgcn_sched_barrier(0);
    __builtin_amdgcn_s_setprio(1);
    #pragma unroll
    for (int m = 0; m < 4; ++m)
      #pragma unroll
      for (int n = 0; n < 4; ++n)
        acc[mq * 4 + m][n] = __builtin_amdgcn_mfma_f32_16x16x32_bf16(
            af[m], bf[n], acc[mq * 4 + m][n], 0, 0, 0);
    __builtin_amdgcn_s_setprio(0);
    if (vm >= 0) vmwait(vm);
    __builtin_amdgcn_s_barrier();
  };

  // prologue: stage half-tiles h0..h4 (stream order), wait h0,h1, barrier.
  stage(0, 0, 0, 0);  // h0: A ks0 (t0)
  stage(1, 0, 0, 0);  // h1: B ks0 (t0)
  stage(0, 0, 1, 0);  // h2: A ks1 (t0)
  stage(1, 0, 1, 0);  // h3: B ks1 (t0)
  stage(0, 1, 0, 1);  // h4: A ks0 (t1)
  vmwait(6);
  __builtin_amdgcn_s_barrier();

  for (int i = 0; i < NTK / 2; ++i) {
    const int t0 = 2 * i, t1 = 2 * i + 1;
    // vmcnt tail drain: vmP1(t)=2*clamp(4NTK-4t-4,0,3), vmP3(t)=2*clamp(4NTK-4t-6,0,3)
    int v1a = 4 * NTK - 4 * t0 - 4; v1a = v1a > 3 ? 3 : (v1a < 0 ? 0 : v1a); v1a *= 2;
    int v3a = 4 * NTK - 4 * t0 - 6; v3a = v3a > 3 ? 3 : (v3a < 0 ? 0 : v3a); v3a *= 2;
    int v1b = 4 * NTK - 4 * t1 - 4; v1b = v1b > 3 ? 3 : (v1b < 0 ? 0 : v1b); v1b *= 2;
    int v3b = 4 * NTK - 4 * t1 - 6; v3b = v3b > 3 ? 3 : (v3b < 0 ? 0 : v3b); v3b *= 2;
    // K-tile t0 (dbuf 0); stages h=4*t0+5..8 in order
    phase(0, 0, 0, true,  1, 1, 0, t0 + 1, -1);   // P0: A[ks0,mq0]+B[ks0]; stage B-ks0(t0+1)->d1
    phase(0, 0, 1, false, 0, 1, 1, t0 + 1, v1a);  // P1: A[ks0,mq1];        stage A-ks1(t0+1)->d1
    phase(0, 1, 0, true,  1, 1, 1, t0 + 1, -1);   // P2: A[ks1,mq0]+B[ks1]; stage B-ks1(t0+1)->d1
    phase(0, 1, 1, false, 0, 0, 0, t0 + 2, v3a);  // P3: A[ks1,mq1];        stage A-ks0(t0+2)->d0
    // K-tile t1 (dbuf 1); stages h=4*t1+5..8
    phase(1, 0, 0, true,  1, 0, 0, t1 + 1, -1);
    phase(1, 0, 1, false, 0, 0, 1, t1 + 1, v1b);
    phase(1, 1, 0, true,  1, 0, 1, t1 + 1, -1);
    phase(1, 1, 1, false, 0, 1, 0, t1 + 2, v3b);  // t1+2 odd -> d1
  }

  // C/D: col = lane&15, row = (lane>>4)*4 + j  (verified)
  const int rb = mt * 256 + wm * 128 + ((lane >> 4) << 2);
  if (MODE == 0) {
    u16* H = (u16*)Oall + (size_t)e * TT * FF;
    const int fb = ntl * 128 + wn * 32 + lr;
    #pragma unroll
    for (int m = 0; m < 8; ++m)
      #pragma unroll
      for (int np = 0; np < 2; ++np)
        #pragma unroll
        for (int j = 0; j < 4; ++j) {
          float g = acc[m][2*np][j];
          float u = acc[m][2*np + 1][j];
          float hh = (g / (1.f + __expf(-g))) * u;
          H[(size_t)(rb + m*16 + j) * FF + fb + np*16] = f2u(hh);
        }
  } else {
    float* D = (float*)Oall + (size_t)e * TT * HH;
    const int cb = ntl * 256 + wn * 64 + lr;
    #pragma unroll
    for (int m = 0; m < 8; ++m)
      #pragma unroll
      for (int n = 0; n < 4; ++n)
        #pragma unroll
        for (int j = 0; j < 4; ++j)
          D[(size_t)(rb + m*16 + j) * HH + cb + n*16] = acc[m][n][j];
  }
}

__global__ void k_combine(const float* __restrict__ tw, const int* __restrict__ te,
                          const int* __restrict__ posmap, const float* __restrict__ dcomp,
                          float* __restrict__ out) {
  const int t = blockIdx.x;
  const int c0 = threadIdx.x * 8;
  float a[8] = {0.f, 0.f, 0.f, 0.f, 0.f, 0.f, 0.f, 0.f};
  #pragma unroll
  for (int k = 0; k < KTOP; ++k) {
    const int e = te[t * KTOP + k];
    const float w = tw[t * KTOP + k];
    const int r = posmap[t * NE + e];
    const float* row = dcomp + ((size_t)e * TT + r) * HH + c0;
    const float4 p = ((const float4*)row)[0];
    const float4 q = ((const float4*)row)[1];
    a[0] += w * p.x; a[1] += w * p.y; a[2] += w * p.z; a[3] += w * p.w;
    a[4] += w * q.x; a[5] += w * q.y; a[6] += w * q.z; a[7] += w * q.w;
  }
  float* o = out + (size_t)t * HH + c0;
  ((float4*)o)[0] = (float4){a[0], a[1], a[2], a[3]};
  ((float4*)o)[1] = (float4){a[4], a[5], a[6], a[7]};
}

extern "C" void kernel_launch(void* const* d_in, const int* in_sizes, int n_in,
                              void* d_out, int out_size, void* d_ws, size_t ws_size,
                              hipStream_t stream) {
  const float* x  = (const float*)d_in[0];
  const float* tw = (const float*)d_in[2];
  const int*   te = (const int*)d_in[3];
  const float* w1 = (const float*)d_in[4];
  const float* v1 = (const float*)d_in[5];
  const float* w2 = (const float*)d_in[6];
  float* out = (float*)d_out;

  char* p = (char*)d_ws;
  int*   cnt    = (int*)p;   p += 256;
  int*   tok    = (int*)p;   p += (size_t)NE * TT * 4;
  int*   posmap = (int*)p;   p += (size_t)TT * NE * 4;
  u16*   xb     = (u16*)p;   p += (size_t)TT * HH * 2;            // 8 MB
  u16*   xg     = (u16*)p;   p += (size_t)NE * TT * HH * 2;       // 64 MB
  u16*   w12b   = (u16*)p;   p += (size_t)NE * 2 * FF * HH * 2;   // 268 MB
  u16*   w2tb   = (u16*)p;   p += (size_t)NE * HH * FF * 2;       // 134 MB
  u16*   hc     = (u16*)p;   p += (size_t)NE * TT * FF * 2;       // 134 MB
  float* dcomp  = (float*)p; p += (size_t)NE * TT * HH * 4;       // 134 MB

  k_build<<<NE, 256, 0, stream>>>(te, cnt, tok, posmap);
  k_cast4<<<1024, 256, 0, stream>>>((const float4*)x, (ushort4*)xb, TT * HH / 4);
  k_cast12<<<NE * FF * (HH / 8) / 256, 256, 0, stream>>>(w1, v1, w12b);
  k_tcast<<<dim3(HH / 32, FF / 32, NE), dim3(32, 8), 0, stream>>>(w2, w2tb);
  k_gather<<<dim3(TT, NE), 256, 0, stream>>>(xb, tok, cnt, xg);

  // GLU: 8 e x 32 ntl x 8 mt = 2048 blocks
  gemm256<0><<<2048, 512, 0, stream>>>(xg, w12b, cnt, hc);
  // down: 8 e x 8 ntl x 8 mt = 512 blocks
  gemm256<1><<<512, 512, 0, stream>>>(hc, w2tb, cnt, dcomp);
  k_combine<<<TT, 256, 0, stream>>>(tw, te, posmap, dcomp, out);
}